// Round 1
// baseline (670.775 us; speedup 1.0000x reference)
//
#include <hip/hip_runtime.h>
#include <cstdint>
#include <cstddef>

typedef _Float16 H16;
typedef _Float16 half8 __attribute__((ext_vector_type(8)));
typedef float f32x4 __attribute__((ext_vector_type(4)));

// ---------------- transpose (B,C,H,W) f32 -> (B,H,W,C) f16, C=256 ----------------
__global__ __launch_bounds__(256) void k_transpose(const float* __restrict__ in,
                                                   H16* __restrict__ out,
                                                   int H, int W) {
  __shared__ float t[32][33];
  const int tx = threadIdx.x, ty = threadIdx.y;
  const int w0 = blockIdx.x * 32;
  const int h  = blockIdx.y;
  const int b  = blockIdx.z >> 3;
  const int c0 = (blockIdx.z & 7) * 32;
#pragma unroll
  for (int i = 0; i < 4; ++i) {
    const int c = c0 + ty + 8 * i;
    t[ty + 8 * i][tx] = in[(((size_t)b * 256 + c) * H + h) * W + w0 + tx];
  }
  __syncthreads();
#pragma unroll
  for (int j = 0; j < 4; ++j) {
    const int w = w0 + ty + 8 * j;
    out[(((size_t)b * H + h) * W + w) * 256 + c0 + tx] = (H16)t[tx][ty + 8 * j];
  }
}

// ---------------- conv1_w (F,C,7,7) f32 -> w1t[f][(py*7+px)*256 + c] f16 ----------------
__global__ __launch_bounds__(256) void k_prep_w1(const float* __restrict__ w,
                                                 H16* __restrict__ wt) {
  const int f = blockIdx.x;
  __shared__ __align__(16) H16 l[12544];
  const float* wf = w + (size_t)f * 12544;
  for (int e = threadIdx.x; e < 12544; e += 256) {
    const int cc = e / 49, pp = e % 49;   // input layout: c*49 + p
    l[pp * 256 + cc] = (H16)wf[e];
  }
  __syncthreads();
  H16* of = wt + (size_t)f * 12544;
  for (int ch = threadIdx.x; ch < 1568; ch += 256) {   // 12544/8
    *(uint4*)(of + ch * 8) = *(const uint4*)(l + ch * 8);
  }
}

// ---------------- f32 -> f16 cast (vector) ----------------
__global__ __launch_bounds__(256) void k_cast_f16(const float4* __restrict__ in,
                                                  uint2* __restrict__ out, int n4) {
  const int i = blockIdx.x * 256 + threadIdx.x;
  if (i >= n4) return;
  const float4 v = in[i];
  union { H16 h[4]; uint2 u; } r;
  r.h[0] = (H16)v.x; r.h[1] = (H16)v.y; r.h[2] = (H16)v.z; r.h[3] = (H16)v.w;
  out[i] = r.u;
}

// ---------------- concat logits_w(81,1024) + bbox_w(324,1024) -> w3b(512,1024) f16 ----------------
__global__ __launch_bounds__(256) void k_prep_w3(const float4* __restrict__ lw,
                                                 const float4* __restrict__ bw,
                                                 uint2* __restrict__ out) {
  const int i = blockIdx.x * 256 + threadIdx.x;  // 131072 = 512*1024/4
  const int r = (i * 4) >> 10;
  float4 v;
  if (r < 81)       v = lw[i];
  else if (r < 405) v = bw[i - 20736];           // 81*256
  else              v = make_float4(0.f, 0.f, 0.f, 0.f);
  union { H16 h[4]; uint2 u; } rr;
  rr.h[0] = (H16)v.x; rr.h[1] = (H16)v.y; rr.h[2] = (H16)v.z; rr.h[3] = (H16)v.w;
  out[i] = rr.u;
}

// ---------------- pyramid ROI-align: pooled[m][(py*7+px)*256 + c] f16 ----------------
__global__ __launch_bounds__(256) void k_roialign(const float* __restrict__ rois,
    const H16* __restrict__ f2, const H16* __restrict__ f3,
    const H16* __restrict__ f4, const H16* __restrict__ f5,
    H16* __restrict__ pooled) {
  const int m = blockIdx.x;
  const int c = threadIdx.x;
  H16* outp = pooled + (size_t)m * 12544 + c;
  if (m >= 2000) {            // pad rows for the 2048-row GEMM
#pragma unroll 1
    for (int p = 0; p < 49; ++p) outp[p * 256] = (H16)0.f;
    return;
  }
  const int b = m / 1000;
  const float y1 = rois[m * 4 + 0], x1 = rois[m * 4 + 1];
  const float y2 = rois[m * 4 + 2], x2 = rois[m * 4 + 3];
  const float area = fmaxf((y2 - y1) * (x2 - x1), 1e-12f);
  const float lvl = log2f(sqrtf(area) / 0.21875f);   // 224/1024
  int level = 4 + (int)rintf(lvl);                   // rint = round-half-even, matches jnp.round
  level = level < 2 ? 2 : (level > 5 ? 5 : level);
  const H16* ft; int H;
  if (level == 2)      { ft = f2; H = 256; }
  else if (level == 3) { ft = f3; H = 128; }
  else if (level == 4) { ft = f4; H = 64; }
  else                 { ft = f5; H = 32; }
  const float Hm1 = (float)(H - 1);
  const size_t bbase = (size_t)b * H * H * 256;

  int yi0[7], yi1[7], xi0[7], xi1[7];
  float wy[7], wx[7];
#pragma unroll
  for (int i = 0; i < 7; ++i) {
    const float tt = (float)i / 6.0f;
    const float ys = (y1 + (y2 - y1) * tt) * Hm1;
    const float xs = (x1 + (x2 - x1) * tt) * Hm1;
    const float yf = floorf(ys), xf = floorf(xs);
    wy[i] = ys - yf; wx[i] = xs - xf;
    int yi = (int)yf, xi = (int)xf;
    yi = yi < 0 ? 0 : (yi > H - 1 ? H - 1 : yi);
    xi = xi < 0 ? 0 : (xi > H - 1 ? H - 1 : xi);
    yi0[i] = yi; xi0[i] = xi;
    yi1[i] = (yi + 1 > H - 1) ? H - 1 : yi + 1;
    xi1[i] = (xi + 1 > H - 1) ? H - 1 : xi + 1;
  }
#pragma unroll 1
  for (int p = 0; p < 49; ++p) {
    const int py = p / 7, px = p % 7;
    const size_t r0 = bbase + (size_t)yi0[py] * H * 256;
    const size_t r1 = bbase + (size_t)yi1[py] * H * 256;
    const float f00 = (float)ft[r0 + (size_t)xi0[px] * 256 + c];
    const float f01 = (float)ft[r0 + (size_t)xi1[px] * 256 + c];
    const float f10 = (float)ft[r1 + (size_t)xi0[px] * 256 + c];
    const float f11 = (float)ft[r1 + (size_t)xi1[px] * 256 + c];
    const float a = wy[py], x = wx[px];
    const float val = f00 * (1.f - a) * (1.f - x) + f01 * (1.f - a) * x
                    + f10 * a * (1.f - x) + f11 * a * x;
    outp[p * 256] = (H16)val;
  }
}

// ---------------- f16 GEMM, C[m][n] = sum_k A[m][k]*Bw[n][k], 128x128 tile, BK=32 ----------------
__global__ __launch_bounds__(256) void k_gemm(const H16* __restrict__ A,
                                              const H16* __restrict__ Bw,
                                              float* __restrict__ Cout,
                                              int Nn, int Ktot, int kchunk) {
  __shared__ __align__(16) H16 As[128 * 32];
  __shared__ __align__(16) H16 Bs[128 * 32];
  const int m0 = blockIdx.x * 128;
  const int n0 = blockIdx.y * 128;
  const int k0 = blockIdx.z * kchunk;
  float* __restrict__ Cp = Cout + (size_t)blockIdx.z * ((size_t)2048 * Nn);
  const int tid  = threadIdx.x;
  const int lane = tid & 63;
  const int wave = tid >> 6;
  const int wm = (wave >> 1) * 64;
  const int wn = (wave & 1) * 64;
  const int r1 = tid >> 2, cb = tid & 3;
  const int r2 = r1 + 64;
  const size_t aoff1 = (size_t)(m0 + r1) * Ktot + cb * 8;
  const size_t aoff2 = (size_t)(m0 + r2) * Ktot + cb * 8;
  const size_t boff1 = (size_t)(n0 + r1) * Ktot + cb * 8;
  const size_t boff2 = (size_t)(n0 + r2) * Ktot + cb * 8;
  f32x4 acc[4][4];
#pragma unroll
  for (int i = 0; i < 4; ++i)
#pragma unroll
    for (int j = 0; j < 4; ++j) acc[i][j] = (f32x4){0.f, 0.f, 0.f, 0.f};
  const int fr = lane & 15, fk = (lane >> 4) * 8;
  const int kend = k0 + kchunk;
  for (int k = k0; k < kend; k += 32) {
    const uint4 a0 = *(const uint4*)(A + aoff1 + k);
    const uint4 a1 = *(const uint4*)(A + aoff2 + k);
    const uint4 b0 = *(const uint4*)(Bw + boff1 + k);
    const uint4 b1 = *(const uint4*)(Bw + boff2 + k);
    __syncthreads();   // previous iter's frag reads done before overwrite
    *(uint4*)(As + tid * 8)         = a0;
    *(uint4*)(As + (tid + 256) * 8) = a1;
    *(uint4*)(Bs + tid * 8)         = b0;
    *(uint4*)(Bs + (tid + 256) * 8) = b1;
    __syncthreads();
    half8 af[4], bf[4];
#pragma unroll
    for (int i = 0; i < 4; ++i) af[i] = *(const half8*)(As + (wm + i * 16 + fr) * 32 + fk);
#pragma unroll
    for (int i = 0; i < 4; ++i) bf[i] = *(const half8*)(Bs + (wn + i * 16 + fr) * 32 + fk);
#pragma unroll
    for (int i = 0; i < 4; ++i)
#pragma unroll
      for (int j = 0; j < 4; ++j)
        acc[i][j] = __builtin_amdgcn_mfma_f32_16x16x32_f16(af[i], bf[j], acc[i][j], 0, 0, 0);
  }
  // C/D layout (measured m89/m91): col = lane&15, row = (lane>>4)*4 + reg
  const int fq = lane >> 4;
#pragma unroll
  for (int i = 0; i < 4; ++i)
#pragma unroll
    for (int j = 0; j < 4; ++j) {
      const int col = n0 + wn + j * 16 + fr;
#pragma unroll
      for (int q = 0; q < 4; ++q) {
        const int row = m0 + wm + i * 16 + fq * 4 + q;
        Cp[(size_t)row * Nn + col] = acc[i][j][q];
      }
    }
}

// ---------------- sum 4 split-K partials ----------------
__global__ __launch_bounds__(256) void k_reduce4(const float4* __restrict__ part,
                                                 float4* __restrict__ x1) {
  const int i = blockIdx.x * 256 + threadIdx.x;   // 524288 float4s
  const float4 a = part[i], b = part[i + 524288], c = part[i + 1048576], d = part[i + 1572864];
  float4 r;
  r.x = a.x + b.x + c.x + d.x; r.y = a.y + b.y + c.y + d.y;
  r.z = a.z + b.z + c.z + d.z; r.w = a.w + b.w + c.w + d.w;
  x1[i] = r;
}

// ---------------- BN (over N=1000 per (b,f)) + ReLU + f16 cast ----------------
__global__ __launch_bounds__(256) void k_bn_relu(const float* __restrict__ X,
                                                 H16* __restrict__ Y,
                                                 const float* __restrict__ gamma,
                                                 const float* __restrict__ beta) {
  const int b  = blockIdx.x >> 5;
  const int fb = (blockIdx.x & 31) * 32;
  const int tf = threadIdx.x & 31;
  const int tn = threadIdx.x >> 5;
  const int f  = fb + tf;
  const size_t base = (size_t)b * 1000 * 1024 + f;
  float s = 0.f, ss = 0.f;
  for (int n = tn; n < 1000; n += 8) {
    const float v = X[base + (size_t)n * 1024];
    s += v; ss += v * v;
  }
  __shared__ float rs[8][32], rq[8][32], mus[32], rstds[32];
  rs[tn][tf] = s; rq[tn][tf] = ss;
  __syncthreads();
  if (threadIdx.x < 32) {
    float S = 0.f, Q = 0.f;
#pragma unroll
    for (int i = 0; i < 8; ++i) { S += rs[i][threadIdx.x]; Q += rq[i][threadIdx.x]; }
    const float mu  = S / 1000.0f;
    const float var = Q / 1000.0f - mu * mu;
    mus[threadIdx.x]   = mu;
    rstds[threadIdx.x] = rsqrtf(var + 1e-5f);
  }
  __syncthreads();
  const float mu = mus[tf], rstd = rstds[tf];
  const float g = gamma[f], bt = beta[f];
  for (int n = tn; n < 1000; n += 8) {
    const size_t ix = base + (size_t)n * 1024;
    const float v = g * (X[ix] - mu) * rstd + bt;
    Y[ix] = (H16)fmaxf(v, 0.f);
  }
}

// ---------------- heads epilogue: bias + softmax + scatter outputs ----------------
__global__ __launch_bounds__(64) void k_head(const float* __restrict__ Z,
                                             const float* __restrict__ lb,
                                             const float* __restrict__ bb,
                                             float* __restrict__ out) {
  const int m = blockIdx.x;        // 0..1999
  const int lane = threadIdx.x;    // 64
  const float* zr = Z + (size_t)m * 512;
  float* outL = out;
  float* outP = out + 162000;
  float* outB = out + 324000;
  const float v0 = zr[lane] + lb[lane];
  const float v1 = (lane < 17) ? (zr[64 + lane] + lb[64 + lane]) : -3.0e38f;
  outL[(size_t)m * 81 + lane] = v0;
  if (lane < 17) outL[(size_t)m * 81 + 64 + lane] = v1;
  float mx = fmaxf(v0, v1);
#pragma unroll
  for (int off = 32; off > 0; off >>= 1) mx = fmaxf(mx, __shfl_xor(mx, off));
  const float e0 = expf(v0 - mx);
  const float e1 = (lane < 17) ? expf(v1 - mx) : 0.f;
  float sm = e0 + e1;
#pragma unroll
  for (int off = 32; off > 0; off >>= 1) sm += __shfl_xor(sm, off);
  const float inv = 1.0f / sm;
  outP[(size_t)m * 81 + lane] = e0 * inv;
  if (lane < 17) outP[(size_t)m * 81 + 64 + lane] = e1 * inv;
#pragma unroll
  for (int j = 0; j < 6; ++j) {
    const int cc = lane + j * 64;
    if (cc < 324) outB[(size_t)m * 324 + cc] = zr[81 + cc] + bb[cc];
  }
}

extern "C" void kernel_launch(void* const* d_in, const int* in_sizes, int n_in,
                              void* d_out, int out_size, void* d_ws, size_t ws_size,
                              hipStream_t stream) {
  char* ws = (char*)d_ws;
  // phase-1 regions (feature transposes + weights + pooled): 158.5 MiB total
  H16* fT2    = (H16*)(ws);                    // 67108864 B
  H16* fT3    = (H16*)(ws + 67108864);         // 16777216 B
  H16* fT4    = (H16*)(ws + 83886080);         //  4194304 B
  H16* fT5    = (H16*)(ws + 88080384);         //  1048576 B
  H16* w1t    = (H16*)(ws + 89128960);         // 25690112 B
  H16* pooled = (H16*)(ws + 114819072);        // 51380224 B (2048 x 12544)
  // phase-2 aliases (feature transposes are dead after k_roialign)
  float* part = (float*)(ws);                  // 33554432 B (4 x 2048 x 1024)
  float* x1   = (float*)(ws + 33554432);       //  8388608 B
  float* zz   = (float*)(ws + 41943040);       //  4194304 B (2048 x 512)
  H16*   y1   = (H16*)(ws + 67108864);         //  4194304 B
  float* x2   = (float*)(ws + 71303168);       //  8388608 B
  H16*   y2   = (H16*)(ws + 79691776);         //  4194304 B
  H16*   w2b  = (H16*)(ws + 83886080);         //  2097152 B
  H16*   w3b  = (H16*)(ws + 85983232);         //  1048576 B

  const float* rois = (const float*)d_in[0];

  dim3 tb(32, 8, 1);
  k_transpose<<<dim3(8, 256, 16), tb, 0, stream>>>((const float*)d_in[1], fT2, 256, 256);
  k_transpose<<<dim3(4, 128, 16), tb, 0, stream>>>((const float*)d_in[2], fT3, 128, 128);
  k_transpose<<<dim3(2,  64, 16), tb, 0, stream>>>((const float*)d_in[3], fT4,  64,  64);
  k_transpose<<<dim3(1,  32, 16), tb, 0, stream>>>((const float*)d_in[4], fT5,  32,  32);
  k_prep_w1<<<1024, 256, 0, stream>>>((const float*)d_in[5], w1t);
  k_roialign<<<2048, 256, 0, stream>>>(rois, fT2, fT3, fT4, fT5, pooled);
  // feature transposes dead now -> safe to overwrite their regions
  k_cast_f16<<<1024, 256, 0, stream>>>((const float4*)d_in[9], (uint2*)w2b, 262144);
  k_prep_w3<<<512, 256, 0, stream>>>((const float4*)d_in[13], (const float4*)d_in[15], (uint2*)w3b);

  // conv1: 2048 x 1024 x 12544, split-K=4
  k_gemm<<<dim3(16, 8, 4), 256, 0, stream>>>(pooled, w1t, part, 1024, 12544, 3136);
  k_reduce4<<<2048, 256, 0, stream>>>((const float4*)part, (float4*)x1);

  hipMemsetAsync(y1, 0, 4194304, stream);      // zero pad rows 2000..2047
  k_bn_relu<<<64, 256, 0, stream>>>(x1, y1, (const float*)d_in[7], (const float*)d_in[8]);

  // conv2: 2048 x 1024 x 1024
  k_gemm<<<dim3(16, 8, 1), 256, 0, stream>>>(y1, w2b, x2, 1024, 1024, 1024);

  hipMemsetAsync(y2, 0, 4194304, stream);
  k_bn_relu<<<64, 256, 0, stream>>>(x2, y2, (const float*)d_in[11], (const float*)d_in[12]);

  // heads: 2048 x 512 x 1024 (rows 0..80 logits, 81..404 bbox, rest zero-pad)
  k_gemm<<<dim3(16, 4, 1), 256, 0, stream>>>(y2, w3b, zz, 512, 1024, 1024);
  k_head<<<2000, 64, 0, stream>>>(zz, (const float*)d_in[14], (const float*)d_in[16], (float*)d_out);
}

// Round 2
// 527.844 us; speedup vs baseline: 1.2708x; 1.2708x over previous
//
#include <hip/hip_runtime.h>
#include <cstdint>
#include <cstddef>

typedef _Float16 H16;
typedef _Float16 half8 __attribute__((ext_vector_type(8)));
typedef float f32x4 __attribute__((ext_vector_type(4)));

typedef __attribute__((address_space(1))) const unsigned int gu32;
typedef __attribute__((address_space(3))) unsigned int lu32;
__device__ __forceinline__ void glds16(const void* g, void* l) {
  __builtin_amdgcn_global_load_lds((gu32*)g, (lu32*)l, 16, 0, 0);
}

// ---------------- transpose (B,C,H,W) f32 -> (B,H,W,C) f16, C=256 ----------------
// block: one (b,h) x 32-w strip, all 256 c. LDS t[w][c] stride 257 (+1 pad).
__global__ __launch_bounds__(256) void k_transpose(const float* __restrict__ in,
                                                   H16* __restrict__ out,
                                                   int H, int W) {
  __shared__ float t[32 * 257];
  const int tid = threadIdx.x;
  const int w0 = blockIdx.x * 32;
  const int h  = blockIdx.y;
  const int b  = blockIdx.z;
  const size_t HW = (size_t)H * W;
  // load: lanes map to w (coalesced float4), c = i*32 + tid>>3
  const int cL = tid >> 3;
  const int w4 = (tid & 7) * 4;
  const float* src = in + (size_t)b * 256 * HW + (size_t)h * W + w0;
#pragma unroll
  for (int i = 0; i < 8; ++i) {
    const int c = i * 32 + cL;
    const float4 v = *(const float4*)(src + (size_t)c * HW + w4);
    t[(w4 + 0) * 257 + c] = v.x;
    t[(w4 + 1) * 257 + c] = v.y;
    t[(w4 + 2) * 257 + c] = v.z;
    t[(w4 + 3) * 257 + c] = v.w;
  }
  __syncthreads();
  // store: w = (tid&3)*8 + j (varies within wave -> banks spread), c4 = (tid>>2)*4
  const int wS = (tid & 3) * 8;
  const int c4 = (tid >> 2) * 4;
  H16* dst = out + ((size_t)b * H + h) * W * 256;
#pragma unroll
  for (int j = 0; j < 8; ++j) {
    const int w = wS + j;
    const float a0 = t[w * 257 + c4 + 0];
    const float a1 = t[w * 257 + c4 + 1];
    const float a2 = t[w * 257 + c4 + 2];
    const float a3 = t[w * 257 + c4 + 3];
    union { H16 hh[4]; uint2 u; } r;
    r.hh[0] = (H16)a0; r.hh[1] = (H16)a1; r.hh[2] = (H16)a2; r.hh[3] = (H16)a3;
    *(uint2*)(dst + (size_t)(w0 + w) * 256 + c4) = r.u;
  }
}

// ---------------- conv1_w (F,C,7,7) f32 -> w1t[f][(py*7+px)*256 + c] f16 ----------------
__global__ __launch_bounds__(256) void k_prep_w1(const float* __restrict__ w,
                                                 H16* __restrict__ wt) {
  const int f = blockIdx.x;
  __shared__ __align__(16) H16 l[12544];
  const float* wf = w + (size_t)f * 12544;
  for (int e = threadIdx.x; e < 12544; e += 256) {
    const int cc = e / 49, pp = e % 49;
    l[pp * 256 + cc] = (H16)wf[e];
  }
  __syncthreads();
  H16* of = wt + (size_t)f * 12544;
  for (int ch = threadIdx.x; ch < 1568; ch += 256) {
    *(uint4*)(of + ch * 8) = *(const uint4*)(l + ch * 8);
  }
}

// ---------------- f32 -> f16 cast (vector) ----------------
__global__ __launch_bounds__(256) void k_cast_f16(const float4* __restrict__ in,
                                                  uint2* __restrict__ out, int n4) {
  const int i = blockIdx.x * 256 + threadIdx.x;
  if (i >= n4) return;
  const float4 v = in[i];
  union { H16 hh[4]; uint2 u; } r;
  r.hh[0] = (H16)v.x; r.hh[1] = (H16)v.y; r.hh[2] = (H16)v.z; r.hh[3] = (H16)v.w;
  out[i] = r.u;
}

// ---------------- concat logits_w(81,1024) + bbox_w(324,1024) -> w3b(512,1024) f16 ----------------
__global__ __launch_bounds__(256) void k_prep_w3(const float4* __restrict__ lw,
                                                 const float4* __restrict__ bw,
                                                 uint2* __restrict__ out) {
  const int i = blockIdx.x * 256 + threadIdx.x;  // 131072
  const int r = (i * 4) >> 10;
  float4 v;
  if (r < 81)       v = lw[i];
  else if (r < 405) v = bw[i - 20736];
  else              v = make_float4(0.f, 0.f, 0.f, 0.f);
  union { H16 hh[4]; uint2 u; } rr;
  rr.hh[0] = (H16)v.x; rr.hh[1] = (H16)v.y; rr.hh[2] = (H16)v.z; rr.hh[3] = (H16)v.w;
  out[i] = rr.u;
}

// ---------------- pyramid ROI-align: 4 channels/thread, uint2 taps ----------------
__global__ __launch_bounds__(256) void k_roialign(const float* __restrict__ rois,
    const H16* __restrict__ f2, const H16* __restrict__ f3,
    const H16* __restrict__ f4p, const H16* __restrict__ f5,
    H16* __restrict__ pooled) {
  const int m = blockIdx.x;
  const int g  = threadIdx.x >> 6;          // p-group 0..3
  const int c4 = (threadIdx.x & 63) * 4;    // 4 channels
  H16* outp = pooled + (size_t)m * 12544 + c4;
  if (m >= 2000) {
    const uint2 z = make_uint2(0u, 0u);
    for (int p = g; p < 49; p += 4) *(uint2*)(outp + p * 256) = z;
    return;
  }
  const int b = (m >= 1000) ? 1 : 0;
  const float y1v = rois[m * 4 + 0], x1v = rois[m * 4 + 1];
  const float y2v = rois[m * 4 + 2], x2v = rois[m * 4 + 3];
  const float dy = y2v - y1v, dx = x2v - x1v;
  const float area = fmaxf(dy * dx, 1e-12f);
  const float lvl = log2f(sqrtf(area) / 0.21875f);
  int level = 4 + (int)rintf(lvl);
  level = level < 2 ? 2 : (level > 5 ? 5 : level);
  const H16* ft; int H;
  if (level == 2)      { ft = f2; H = 256; }
  else if (level == 3) { ft = f3; H = 128; }
  else if (level == 4) { ft = f4p; H = 64; }
  else                 { ft = f5; H = 32; }
  const float Hm1 = (float)(H - 1);
  const size_t bbase = (size_t)b * H * H * 256;
#pragma unroll 1
  for (int p = g; p < 49; p += 4) {
    const int py = (p * 147) >> 10;        // p/7 for p<49
    const int px = p - py * 7;
    const float ys = (y1v + dy * (py * 0.16666667f)) * Hm1;
    const float xs = (x1v + dx * (px * 0.16666667f)) * Hm1;
    const float yf = floorf(ys), xf = floorf(xs);
    const float wyv = ys - yf, wxv = xs - xf;
    int yi = (int)yf, xi = (int)xf;
    yi = yi < 0 ? 0 : (yi > H - 1 ? H - 1 : yi);
    xi = xi < 0 ? 0 : (xi > H - 1 ? H - 1 : xi);
    const int yiB = (yi + 1 > H - 1) ? H - 1 : yi + 1;
    const int xiB = (xi + 1 > H - 1) ? H - 1 : xi + 1;
    const size_t r0 = bbase + (size_t)yi * H * 256;
    const size_t r1 = bbase + (size_t)yiB * H * 256;
    union { uint2 u; H16 hh[4]; } v00, v01, v10, v11;
    v00.u = *(const uint2*)(ft + r0 + (size_t)xi  * 256 + c4);
    v01.u = *(const uint2*)(ft + r0 + (size_t)xiB * 256 + c4);
    v10.u = *(const uint2*)(ft + r1 + (size_t)xi  * 256 + c4);
    v11.u = *(const uint2*)(ft + r1 + (size_t)xiB * 256 + c4);
    const float w00 = (1.f - wyv) * (1.f - wxv);
    const float w01 = (1.f - wyv) * wxv;
    const float w10 = wyv * (1.f - wxv);
    const float w11 = wyv * wxv;
    union { H16 hh[4]; uint2 u; } r;
#pragma unroll
    for (int q = 0; q < 4; ++q) {
      const float val = (float)v00.hh[q] * w00 + (float)v01.hh[q] * w01
                      + (float)v10.hh[q] * w10 + (float)v11.hh[q] * w11;
      r.hh[q] = (H16)val;
    }
    *(uint2*)(outp + p * 256) = r.u;
  }
}

// ---------------- f16 GEMM, m97-style: global_load_lds width-16 staging ----------------
__global__ __launch_bounds__(256) void k_gemm(const H16* __restrict__ A,
                                              const H16* __restrict__ Bw,
                                              float* __restrict__ Cout,
                                              int Nn, int Ktot, int kchunk) {
  __shared__ __align__(16) H16 As[128 * 32];
  __shared__ __align__(16) H16 Bs[128 * 32];
  const int m0 = blockIdx.x * 128;
  const int n0 = blockIdx.y * 128;
  const int k0 = blockIdx.z * kchunk;
  float* __restrict__ Cp = Cout + (size_t)blockIdx.z * ((size_t)2048 * Nn);
  const int tid  = threadIdx.x;
  const int lane = tid & 63;
  const int wave = tid >> 6;
  const int wm = (wave >> 1) * 64;
  const int wn = (wave & 1) * 64;
  const int r1 = tid >> 2;
  const int cb = (tid & 3) * 8;
  const H16* gA1 = A  + (size_t)(m0 + r1) * Ktot + cb + k0;
  const H16* gA2 = A  + (size_t)(m0 + 64 + r1) * Ktot + cb + k0;
  const H16* gB1 = Bw + (size_t)(n0 + r1) * Ktot + cb + k0;
  const H16* gB2 = Bw + (size_t)(n0 + 64 + r1) * Ktot + cb + k0;
  H16* lA1 = As + tid * 8;          // linear: lane*16B within wave-uniform base
  H16* lA2 = As + 2048 + tid * 8;
  H16* lB1 = Bs + tid * 8;
  H16* lB2 = Bs + 2048 + tid * 8;
  f32x4 acc[4][4];
#pragma unroll
  for (int i = 0; i < 4; ++i)
#pragma unroll
    for (int j = 0; j < 4; ++j) acc[i][j] = (f32x4){0.f, 0.f, 0.f, 0.f};
  const int fr = lane & 15, fk = (lane >> 4) * 8;
  const int niter = kchunk >> 5;
  for (int it = 0; it < niter; ++it) {
    __syncthreads();                 // prior frag reads done before LDS overwrite
    glds16(gA1, lA1); glds16(gA2, lA2);
    glds16(gB1, lB1); glds16(gB2, lB2);
    gA1 += 32; gA2 += 32; gB1 += 32; gB2 += 32;
    __syncthreads();                 // vmcnt(0)+barrier: tile resident
    half8 af[4], bf[4];
#pragma unroll
    for (int i = 0; i < 4; ++i) af[i] = *(const half8*)(As + (wm + i * 16 + fr) * 32 + fk);
#pragma unroll
    for (int i = 0; i < 4; ++i) bf[i] = *(const half8*)(Bs + (wn + i * 16 + fr) * 32 + fk);
#pragma unroll
    for (int i = 0; i < 4; ++i)
#pragma unroll
      for (int j = 0; j < 4; ++j)
        acc[i][j] = __builtin_amdgcn_mfma_f32_16x16x32_f16(af[i], bf[j], acc[i][j], 0, 0, 0);
  }
  // C/D layout: col = lane&15, row = (lane>>4)*4 + reg  [m89/m91]
  const int fq = lane >> 4;
#pragma unroll
  for (int i = 0; i < 4; ++i)
#pragma unroll
    for (int j = 0; j < 4; ++j) {
      const int col = n0 + wn + j * 16 + fr;
#pragma unroll
      for (int q = 0; q < 4; ++q) {
        const int row = m0 + wm + i * 16 + fq * 4 + q;
        Cp[(size_t)row * Nn + col] = acc[i][j][q];
      }
    }
}

// ---------------- sum 4 split-K partials ----------------
__global__ __launch_bounds__(256) void k_reduce4(const float4* __restrict__ part,
                                                 float4* __restrict__ x1) {
  const int i = blockIdx.x * 256 + threadIdx.x;   // 524288 float4s
  const float4 a = part[i], b = part[i + 524288], c = part[i + 1048576], d = part[i + 1572864];
  float4 r;
  r.x = a.x + b.x + c.x + d.x; r.y = a.y + b.y + c.y + d.y;
  r.z = a.z + b.z + c.z + d.z; r.w = a.w + b.w + c.w + d.w;
  x1[i] = r;
}

// ---------------- BN stats: partial sums over 40-row chunks ----------------
__global__ __launch_bounds__(256) void k_bn_stats(const float* __restrict__ X,
                                                  float* __restrict__ psum,
                                                  float* __restrict__ psq) {
  const int nc = blockIdx.x;      // 0..24
  const int b  = blockIdx.y;      // 0..1
  const int f4 = threadIdx.x * 4;
  const float* xp = X + (size_t)(b * 1000 + nc * 40) * 1024 + f4;
  float4 s = {0.f, 0.f, 0.f, 0.f}, q = {0.f, 0.f, 0.f, 0.f};
  for (int r = 0; r < 40; ++r) {
    const float4 v = *(const float4*)(xp + (size_t)r * 1024);
    s.x += v.x; s.y += v.y; s.z += v.z; s.w += v.w;
    q.x += v.x * v.x; q.y += v.y * v.y; q.z += v.z * v.z; q.w += v.w * v.w;
  }
  const size_t o = (size_t)(b * 25 + nc) * 1024 + f4;
  *(float4*)(psum + o) = s;
  *(float4*)(psq + o)  = q;
}

// ---------------- BN finalize: mu/var -> affine coeff (a, c) ----------------
__global__ __launch_bounds__(256) void k_bn_fin(const float* __restrict__ psum,
                                                const float* __restrict__ psq,
                                                const float* __restrict__ gamma,
                                                const float* __restrict__ beta,
                                                float* __restrict__ coeff) {
  const int idx = blockIdx.x * 256 + threadIdx.x;   // 0..2047
  const int b = idx >> 10, f = idx & 1023;
  float S = 0.f, Q = 0.f;
  for (int i = 0; i < 25; ++i) {
    S += psum[(size_t)(b * 25 + i) * 1024 + f];
    Q += psq[(size_t)(b * 25 + i) * 1024 + f];
  }
  const float mu   = S * 0.001f;
  const float var  = Q * 0.001f - mu * mu;
  const float rstd = rsqrtf(var + 1e-5f);
  const float a = gamma[f] * rstd;
  coeff[idx * 2]     = a;
  coeff[idx * 2 + 1] = beta[f] - mu * a;
}

// ---------------- BN apply + ReLU + f16 (zeroes pad rows) ----------------
__global__ __launch_bounds__(256) void k_bn_apply(const float* __restrict__ X,
                                                  const float* __restrict__ coeff,
                                                  H16* __restrict__ Y) {
  const int idx = blockIdx.x * 256 + threadIdx.x;   // 0..524287
  const int m  = idx >> 8;
  const int f4 = (idx & 255) * 4;
  union { H16 hh[4]; uint2 u; } r;
  if (m >= 2000) {
    r.hh[0] = r.hh[1] = r.hh[2] = r.hh[3] = (H16)0.f;
    *(uint2*)(Y + (size_t)idx * 4) = r.u;
    return;
  }
  const int b = (m >= 1000) ? 1 : 0;
  const float4 v   = *(const float4*)(X + (size_t)idx * 4);
  const float4 c01 = *(const float4*)(coeff + b * 2048 + f4 * 2);
  const float4 c23 = *(const float4*)(coeff + b * 2048 + f4 * 2 + 4);
  r.hh[0] = (H16)fmaxf(c01.x * v.x + c01.y, 0.f);
  r.hh[1] = (H16)fmaxf(c01.z * v.y + c01.w, 0.f);
  r.hh[2] = (H16)fmaxf(c23.x * v.z + c23.y, 0.f);
  r.hh[3] = (H16)fmaxf(c23.z * v.w + c23.w, 0.f);
  *(uint2*)(Y + (size_t)idx * 4) = r.u;
}

// ---------------- heads epilogue: bias + softmax + scatter outputs ----------------
__global__ __launch_bounds__(64) void k_head(const float* __restrict__ Z,
                                             const float* __restrict__ lb,
                                             const float* __restrict__ bb,
                                             float* __restrict__ out) {
  const int m = blockIdx.x;        // 0..1999
  const int lane = threadIdx.x;
  const float* zr = Z + (size_t)m * 512;
  float* outL = out;
  float* outP = out + 162000;
  float* outB = out + 324000;
  const float v0 = zr[lane] + lb[lane];
  const float v1 = (lane < 17) ? (zr[64 + lane] + lb[64 + lane]) : -3.0e38f;
  outL[(size_t)m * 81 + lane] = v0;
  if (lane < 17) outL[(size_t)m * 81 + 64 + lane] = v1;
  float mx = fmaxf(v0, v1);
#pragma unroll
  for (int off = 32; off > 0; off >>= 1) mx = fmaxf(mx, __shfl_xor(mx, off));
  const float e0 = expf(v0 - mx);
  const float e1 = (lane < 17) ? expf(v1 - mx) : 0.f;
  float sm = e0 + e1;
#pragma unroll
  for (int off = 32; off > 0; off >>= 1) sm += __shfl_xor(sm, off);
  const float inv = 1.0f / sm;
  outP[(size_t)m * 81 + lane] = e0 * inv;
  if (lane < 17) outP[(size_t)m * 81 + 64 + lane] = e1 * inv;
#pragma unroll
  for (int j = 0; j < 6; ++j) {
    const int cc = lane + j * 64;
    if (cc < 324) outB[(size_t)m * 324 + cc] = zr[81 + cc] + bb[cc];
  }
}

extern "C" void kernel_launch(void* const* d_in, const int* in_sizes, int n_in,
                              void* d_out, int out_size, void* d_ws, size_t ws_size,
                              hipStream_t stream) {
  char* ws = (char*)d_ws;
  // phase-1 regions
  H16* fT2    = (H16*)(ws);                    // 67108864 B
  H16* fT3    = (H16*)(ws + 67108864);         // 16777216 B
  H16* fT4    = (H16*)(ws + 83886080);         //  4194304 B
  H16* fT5    = (H16*)(ws + 88080384);         //  1048576 B
  H16* w1t    = (H16*)(ws + 89128960);         // 25690112 B
  H16* pooled = (H16*)(ws + 114819072);        // 51380224 B (2048 x 12544)
  // phase-2 aliases (features dead after k_roialign)
  float* part  = (float*)(ws);                 // 33554432 B
  float* x1    = (float*)(ws + 33554432);      //  8388608 B
  float* zz    = (float*)(ws + 41943040);      //  4194304 B
  H16*   y1    = (H16*)(ws + 67108864);        //  4194304 B
  float* x2    = (float*)(ws + 71303168);      //  8388608 B
  H16*   y2    = (H16*)(ws + 79691776);        //  4194304 B
  H16*   w2b   = (H16*)(ws + 83886080);        //  2097152 B
  H16*   w3b   = (H16*)(ws + 85983232);        //  1048576 B
  float* psum  = (float*)(ws + 87031808);      //   204800 B
  float* psq   = (float*)(ws + 87236608);      //   204800 B
  float* coef1 = (float*)(ws + 87441408);      //    16384 B
  float* coef2 = (float*)(ws + 87457792);      //    16384 B

  const float* rois = (const float*)d_in[0];

  k_transpose<<<dim3(8, 256, 2), 256, 0, stream>>>((const float*)d_in[1], fT2, 256, 256);
  k_transpose<<<dim3(4, 128, 2), 256, 0, stream>>>((const float*)d_in[2], fT3, 128, 128);
  k_transpose<<<dim3(2,  64, 2), 256, 0, stream>>>((const float*)d_in[3], fT4,  64,  64);
  k_transpose<<<dim3(1,  32, 2), 256, 0, stream>>>((const float*)d_in[4], fT5,  32,  32);
  k_prep_w1<<<1024, 256, 0, stream>>>((const float*)d_in[5], w1t);
  k_roialign<<<2048, 256, 0, stream>>>(rois, fT2, fT3, fT4, fT5, pooled);
  // features dead -> safe to overwrite their regions
  k_cast_f16<<<1024, 256, 0, stream>>>((const float4*)d_in[9], (uint2*)w2b, 262144);
  k_prep_w3<<<512, 256, 0, stream>>>((const float4*)d_in[13], (const float4*)d_in[15], (uint2*)w3b);

  // conv1: 2048 x 1024 x 12544, split-K=4
  k_gemm<<<dim3(16, 8, 4), 256, 0, stream>>>(pooled, w1t, part, 1024, 12544, 3136);
  k_reduce4<<<2048, 256, 0, stream>>>((const float4*)part, (float4*)x1);

  k_bn_stats<<<dim3(25, 2), 256, 0, stream>>>(x1, psum, psq);
  k_bn_fin<<<8, 256, 0, stream>>>(psum, psq, (const float*)d_in[7], (const float*)d_in[8], coef1);
  k_bn_apply<<<2048, 256, 0, stream>>>(x1, coef1, y1);

  // conv2: 2048 x 1024 x 1024
  k_gemm<<<dim3(16, 8, 1), 256, 0, stream>>>(y1, w2b, x2, 1024, 1024, 1024);

  k_bn_stats<<<dim3(25, 2), 256, 0, stream>>>(x2, psum, psq);
  k_bn_fin<<<8, 256, 0, stream>>>(psum, psq, (const float*)d_in[11], (const float*)d_in[12], coef2);
  k_bn_apply<<<2048, 256, 0, stream>>>(x2, coef2, y2);

  // heads: 2048 x 512 x 1024
  k_gemm<<<dim3(16, 4, 1), 256, 0, stream>>>(y2, w3b, zz, 512, 1024, 1024);
  k_head<<<2000, 64, 0, stream>>>(zz, (const float*)d_in[14], (const float*)d_in[16], (float*)d_out);
}

// Round 4
// 505.197 us; speedup vs baseline: 1.3277x; 1.0448x over previous
//
#include <hip/hip_runtime.h>
#include <cstdint>
#include <cstddef>

typedef _Float16 H16;
typedef _Float16 half8 __attribute__((ext_vector_type(8)));
typedef float f32x4 __attribute__((ext_vector_type(4)));

typedef __attribute__((address_space(1))) const unsigned int gu32;
typedef __attribute__((address_space(3))) unsigned int lu32;
__device__ __forceinline__ void glds16(const void* g, void* l) {
  __builtin_amdgcn_global_load_lds((gu32*)g, (lu32*)l, 16, 0, 0);
}

// ---------------- all 4 feature transposes (B,C,H,W) f32 -> (B,H,W,C) f16 ----------------
// 1D grid: p2 strips [0,4096), p3 [4096,5120), p4 [5120,5376), p5 [5376,5440)
__global__ __launch_bounds__(256) void k_transpose_all(
    const float* __restrict__ p2, const float* __restrict__ p3,
    const float* __restrict__ p4, const float* __restrict__ p5,
    H16* __restrict__ o2, H16* __restrict__ o3,
    H16* __restrict__ o4, H16* __restrict__ o5) {
  __shared__ float t[32 * 257];
  const int tid = threadIdx.x;
  int bid = blockIdx.x;
  const float* in; H16* out; int H;
  if (bid < 4096)      { in = p2; out = o2; H = 256; }
  else if (bid < 5120) { in = p3; out = o3; H = 128; bid -= 4096; }
  else if (bid < 5376) { in = p4; out = o4; H = 64;  bid -= 5120; }
  else                 { in = p5; out = o5; H = 32;  bid -= 5376; }
  const int wpb = H >> 5;
  const int strips = wpb * H;
  const int b = (bid >= strips) ? 1 : 0;
  bid -= b ? strips : 0;
  const int h = bid / wpb;
  const int w0 = (bid - h * wpb) * 32;
  const size_t HW = (size_t)H * H;
  // load: 8 lanes * float4 cover the 32-w strip; 8 c-planes per iter
  const int cL = tid >> 3;
  const int w4 = (tid & 7) * 4;
  const float* src = in + (size_t)b * 256 * HW + (size_t)h * H + w0;
#pragma unroll
  for (int i = 0; i < 8; ++i) {
    const int c = i * 32 + cL;
    const float4 v = *(const float4*)(src + (size_t)c * HW + w4);
    t[(w4 + 0) * 257 + c] = v.x;
    t[(w4 + 1) * 257 + c] = v.y;
    t[(w4 + 2) * 257 + c] = v.z;
    t[(w4 + 3) * 257 + c] = v.w;
  }
  __syncthreads();
  // store: each wave writes one full 512B output row
  const int wS = tid >> 6;              // 0..3
  const int c4 = (tid & 63) * 4;
  H16* dst = out + (((size_t)b * H + h) * H + w0) * 256;
#pragma unroll
  for (int j = 0; j < 8; ++j) {
    const int w = wS + j * 4;
    union { H16 hh[4]; uint2 u; } r;
    r.hh[0] = (H16)t[w * 257 + c4 + 0];
    r.hh[1] = (H16)t[w * 257 + c4 + 1];
    r.hh[2] = (H16)t[w * 257 + c4 + 2];
    r.hh[3] = (H16)t[w * 257 + c4 + 3];
    *(uint2*)(dst + (size_t)w * 256 + c4) = r.u;
  }
}

// ---------------- conv1_w (F,C,7,7) f32 -> w1t[f][(py*7+px)*256 + c] f16 ----------------
// LDS row padded to 264 halfs: write bank = (p*66 + ...)%32 spreads (was 32-way at stride 256)
__global__ __launch_bounds__(256) void k_prep_w1(const float* __restrict__ w,
                                                 H16* __restrict__ wt) {
  const int f = blockIdx.x;
  __shared__ __align__(16) H16 l[49 * 264];
  const float* wf = w + (size_t)f * 12544;
  for (int e = threadIdx.x; e < 12544; e += 256) {
    const int cc = e / 49, pp = e - cc * 49;
    l[pp * 264 + cc] = (H16)wf[e];
  }
  __syncthreads();
  H16* of = wt + (size_t)f * 12544;
  for (int ch = threadIdx.x; ch < 1568; ch += 256) {
    const int p = ch >> 5, c8 = (ch & 31) * 8;
    *(uint4*)(of + (ch << 3)) = *(const uint4*)(l + p * 264 + c8);
  }
}

// ---------------- w2 cast + w3 concat-cast, one kernel ----------------
__global__ __launch_bounds__(256) void k_prep_small(const float4* __restrict__ w2,
                                                    const float4* __restrict__ lw,
                                                    const float4* __restrict__ bw,
                                                    uint2* __restrict__ w2b,
                                                    uint2* __restrict__ w3b) {
  const int bid = blockIdx.x;
  union { H16 hh[4]; uint2 u; } r;
  if (bid < 1024) {
    const int i = bid * 256 + threadIdx.x;      // 262144 float4s
    const float4 v = w2[i];
    r.hh[0] = (H16)v.x; r.hh[1] = (H16)v.y; r.hh[2] = (H16)v.z; r.hh[3] = (H16)v.w;
    w2b[i] = r.u;
  } else {
    const int i = (bid - 1024) * 256 + threadIdx.x;   // 131072
    const int row = (i * 4) >> 10;
    float4 v;
    if (row < 81)       v = lw[i];
    else if (row < 405) v = bw[i - 20736];
    else                v = make_float4(0.f, 0.f, 0.f, 0.f);
    r.hh[0] = (H16)v.x; r.hh[1] = (H16)v.y; r.hh[2] = (H16)v.z; r.hh[3] = (H16)v.w;
    w3b[i] = r.u;
  }
}

// ---------------- pyramid ROI-align: 4 channels/thread, uint2 taps ----------------
__global__ __launch_bounds__(256) void k_roialign(const float* __restrict__ rois,
    const H16* __restrict__ f2, const H16* __restrict__ f3,
    const H16* __restrict__ f4p, const H16* __restrict__ f5,
    H16* __restrict__ pooled) {
  const int m = blockIdx.x;
  const int g  = threadIdx.x >> 6;          // p-group 0..3
  const int c4 = (threadIdx.x & 63) * 4;
  H16* outp = pooled + (size_t)m * 12544 + c4;
  if (m >= 2000) {
    const uint2 z = make_uint2(0u, 0u);
    for (int p = g; p < 49; p += 4) *(uint2*)(outp + p * 256) = z;
    return;
  }
  const int b = (m >= 1000) ? 1 : 0;
  const float y1v = rois[m * 4 + 0], x1v = rois[m * 4 + 1];
  const float y2v = rois[m * 4 + 2], x2v = rois[m * 4 + 3];
  const float dy = y2v - y1v, dx = x2v - x1v;
  const float area = fmaxf(dy * dx, 1e-12f);
  const float lvl = log2f(sqrtf(area) / 0.21875f);
  int level = 4 + (int)rintf(lvl);
  level = level < 2 ? 2 : (level > 5 ? 5 : level);
  const H16* ft; int H;
  if (level == 2)      { ft = f2; H = 256; }
  else if (level == 3) { ft = f3; H = 128; }
  else if (level == 4) { ft = f4p; H = 64; }
  else                 { ft = f5; H = 32; }
  const float Hm1 = (float)(H - 1);
  const size_t bbase = (size_t)b * H * H * 256;
#pragma unroll 1
  for (int p = g; p < 49; p += 4) {
    const int py = (p * 147) >> 10;
    const int px = p - py * 7;
    const float ys = (y1v + dy * (py * 0.16666667f)) * Hm1;
    const float xs = (x1v + dx * (px * 0.16666667f)) * Hm1;
    const float yf = floorf(ys), xf = floorf(xs);
    const float wyv = ys - yf, wxv = xs - xf;
    int yi = (int)yf, xi = (int)xf;
    yi = yi < 0 ? 0 : (yi > H - 1 ? H - 1 : yi);
    xi = xi < 0 ? 0 : (xi > H - 1 ? H - 1 : xi);
    const int yiB = (yi + 1 > H - 1) ? H - 1 : yi + 1;
    const int xiB = (xi + 1 > H - 1) ? H - 1 : xi + 1;
    const size_t r0 = bbase + (size_t)yi * H * 256;
    const size_t r1 = bbase + (size_t)yiB * H * 256;
    union { uint2 u; H16 hh[4]; } v00, v01, v10, v11;
    v00.u = *(const uint2*)(ft + r0 + (size_t)xi  * 256 + c4);
    v01.u = *(const uint2*)(ft + r0 + (size_t)xiB * 256 + c4);
    v10.u = *(const uint2*)(ft + r1 + (size_t)xi  * 256 + c4);
    v11.u = *(const uint2*)(ft + r1 + (size_t)xiB * 256 + c4);
    const float w00 = (1.f - wyv) * (1.f - wxv);
    const float w01 = (1.f - wyv) * wxv;
    const float w10 = wyv * (1.f - wxv);
    const float w11 = wyv * wxv;
    union { H16 hh[4]; uint2 u; } r;
#pragma unroll
    for (int q = 0; q < 4; ++q) {
      const float val = (float)v00.hh[q] * w00 + (float)v01.hh[q] * w01
                      + (float)v10.hh[q] * w10 + (float)v11.hh[q] * w11;
      r.hh[q] = (H16)val;
    }
    *(uint2*)(outp + p * 256) = r.u;
  }
}

// ---------------- f16 GEMM, m97-style: global_load_lds width-16 staging ----------------
__global__ __launch_bounds__(256) void k_gemm(const H16* __restrict__ A,
                                              const H16* __restrict__ Bw,
                                              float* __restrict__ Cout,
                                              int Nn, int Ktot, int kchunk) {
  __shared__ __align__(16) H16 As[128 * 32];
  __shared__ __align__(16) H16 Bs[128 * 32];
  const int m0 = blockIdx.x * 128;
  const int n0 = blockIdx.y * 128;
  const int k0 = blockIdx.z * kchunk;
  float* __restrict__ Cp = Cout + (size_t)blockIdx.z * ((size_t)2048 * Nn);
  const int tid  = threadIdx.x;
  const int lane = tid & 63;
  const int wave = tid >> 6;
  const int wm = (wave >> 1) * 64;
  const int wn = (wave & 1) * 64;
  const int r1 = tid >> 2;
  const int cb = (tid & 3) * 8;
  const H16* gA1 = A  + (size_t)(m0 + r1) * Ktot + cb + k0;
  const H16* gA2 = A  + (size_t)(m0 + 64 + r1) * Ktot + cb + k0;
  const H16* gB1 = Bw + (size_t)(n0 + r1) * Ktot + cb + k0;
  const H16* gB2 = Bw + (size_t)(n0 + 64 + r1) * Ktot + cb + k0;
  H16* lA1 = As + tid * 8;
  H16* lA2 = As + 2048 + tid * 8;
  H16* lB1 = Bs + tid * 8;
  H16* lB2 = Bs + 2048 + tid * 8;
  f32x4 acc[4][4];
#pragma unroll
  for (int i = 0; i < 4; ++i)
#pragma unroll
    for (int j = 0; j < 4; ++j) acc[i][j] = (f32x4){0.f, 0.f, 0.f, 0.f};
  const int fr = lane & 15, fk = (lane >> 4) * 8;
  const int niter = kchunk >> 5;
  for (int it = 0; it < niter; ++it) {
    __syncthreads();
    glds16(gA1, lA1); glds16(gA2, lA2);
    glds16(gB1, lB1); glds16(gB2, lB2);
    gA1 += 32; gA2 += 32; gB1 += 32; gB2 += 32;
    __syncthreads();
    half8 af[4], bf[4];
#pragma unroll
    for (int i = 0; i < 4; ++i) af[i] = *(const half8*)(As + (wm + i * 16 + fr) * 32 + fk);
#pragma unroll
    for (int i = 0; i < 4; ++i) bf[i] = *(const half8*)(Bs + (wn + i * 16 + fr) * 32 + fk);
#pragma unroll
    for (int i = 0; i < 4; ++i)
#pragma unroll
      for (int j = 0; j < 4; ++j)
        acc[i][j] = __builtin_amdgcn_mfma_f32_16x16x32_f16(af[i], bf[j], acc[i][j], 0, 0, 0);
  }
  const int fq = lane >> 4;
#pragma unroll
  for (int i = 0; i < 4; ++i)
#pragma unroll
    for (int j = 0; j < 4; ++j) {
      const int col = n0 + wn + j * 16 + fr;
#pragma unroll
      for (int q = 0; q < 4; ++q) {
        const int row = m0 + wm + i * 16 + fq * 4 + q;
        Cp[(size_t)row * Nn + col] = acc[i][j][q];
      }
    }
}

// ---------------- fused split-K reduce + BN partial stats ----------------
// grid 250 blocks x 8 rows; writes X rows [0,2000) and per-chunk sum/sumsq
__global__ __launch_bounds__(256) void k_red_stats(const float* __restrict__ part,
                                                   float* __restrict__ X,
                                                   float* __restrict__ psum,
                                                   float* __restrict__ psq,
                                                   int nz) {
  const int chunk = blockIdx.x;          // 0..249
  const int r0 = chunk * 8;
  const int f4 = threadIdx.x * 4;
  f32x4 s = {0.f, 0.f, 0.f, 0.f}, q = {0.f, 0.f, 0.f, 0.f};
#pragma unroll 1
  for (int r = 0; r < 8; ++r) {
    const size_t row = r0 + r;
    f32x4 a = {0.f, 0.f, 0.f, 0.f};
    for (int z = 0; z < nz; ++z) {
      const f32x4 v = *(const f32x4*)(part + ((size_t)z * 2048 + row) * 1024 + f4);
      a += v;
    }
    *(f32x4*)(X + row * 1024 + f4) = a;
    s += a; q += a * a;
  }
  *(f32x4*)(psum + (size_t)chunk * 1024 + f4) = s;
  *(f32x4*)(psq  + (size_t)chunk * 1024 + f4) = q;
}

// ---------------- BN finalize: 125 chunks/batch -> affine coeff ----------------
__global__ __launch_bounds__(256) void k_bn_fin(const float* __restrict__ psum,
                                                const float* __restrict__ psq,
                                                const float* __restrict__ gamma,
                                                const float* __restrict__ beta,
                                                float* __restrict__ coeff) {
  const int idx = blockIdx.x * 256 + threadIdx.x;   // 0..2047
  const int b = idx >> 10, f = idx & 1023;
  float S = 0.f, Q = 0.f;
  for (int i = 0; i < 125; ++i) {
    S += psum[(size_t)(b * 125 + i) * 1024 + f];
    Q += psq[(size_t)(b * 125 + i) * 1024 + f];
  }
  const float mu   = S * 0.001f;
  const float var  = Q * 0.001f - mu * mu;
  const float rstd = rsqrtf(var + 1e-5f);
  const float a = gamma[f] * rstd;
  coeff[idx * 2]     = a;
  coeff[idx * 2 + 1] = beta[f] - mu * a;
}

// ---------------- BN apply + ReLU + f16 (zeroes pad rows) ----------------
__global__ __launch_bounds__(256) void k_bn_apply(const float* __restrict__ X,
                                                  const float* __restrict__ coeff,
                                                  H16* __restrict__ Y) {
  const int idx = blockIdx.x * 256 + threadIdx.x;
  const int m  = idx >> 8;
  const int f4 = (idx & 255) * 4;
  union { H16 hh[4]; uint2 u; } r;
  if (m >= 2000) {
    r.hh[0] = r.hh[1] = r.hh[2] = r.hh[3] = (H16)0.f;
    *(uint2*)(Y + (size_t)idx * 4) = r.u;
    return;
  }
  const int b = (m >= 1000) ? 1 : 0;
  const float4 v   = *(const float4*)(X + (size_t)idx * 4);
  const float4 c01 = *(const float4*)(coeff + b * 2048 + f4 * 2);
  const float4 c23 = *(const float4*)(coeff + b * 2048 + f4 * 2 + 4);
  r.hh[0] = (H16)fmaxf(c01.x * v.x + c01.y, 0.f);
  r.hh[1] = (H16)fmaxf(c01.z * v.y + c01.w, 0.f);
  r.hh[2] = (H16)fmaxf(c23.x * v.z + c23.y, 0.f);
  r.hh[3] = (H16)fmaxf(c23.z * v.w + c23.w, 0.f);
  *(uint2*)(Y + (size_t)idx * 4) = r.u;
}

// ---------------- heads epilogue: sum 4 split-K partials + bias + softmax ----------------
__global__ __launch_bounds__(64) void k_head(const float* __restrict__ Zp,
                                             const float* __restrict__ lb,
                                             const float* __restrict__ bb,
                                             float* __restrict__ out) {
  const int m = blockIdx.x;
  const int lane = threadIdx.x;
  const size_t P = (size_t)2048 * 512;
  const float* zr = Zp + (size_t)m * 512;
  float* outL = out;
  float* outP = out + 162000;
  float* outB = out + 324000;
  const float v0 = zr[lane] + zr[P + lane] + zr[2 * P + lane] + zr[3 * P + lane] + lb[lane];
  float v1 = -3.0e38f;
  if (lane < 17) {
    const int c = 64 + lane;
    v1 = zr[c] + zr[P + c] + zr[2 * P + c] + zr[3 * P + c] + lb[c];
  }
  outL[(size_t)m * 81 + lane] = v0;
  if (lane < 17) outL[(size_t)m * 81 + 64 + lane] = v1;
  float mx = fmaxf(v0, v1);
#pragma unroll
  for (int off = 32; off > 0; off >>= 1) mx = fmaxf(mx, __shfl_xor(mx, off));
  const float e0 = expf(v0 - mx);
  const float e1 = (lane < 17) ? expf(v1 - mx) : 0.f;
  float sm = e0 + e1;
#pragma unroll
  for (int off = 32; off > 0; off >>= 1) sm += __shfl_xor(sm, off);
  const float inv = 1.0f / sm;
  outP[(size_t)m * 81 + lane] = e0 * inv;
  if (lane < 17) outP[(size_t)m * 81 + 64 + lane] = e1 * inv;
#pragma unroll
  for (int j = 0; j < 6; ++j) {
    const int cc = lane + j * 64;
    if (cc < 324) {
      const int c = 81 + cc;
      outB[(size_t)m * 324 + cc] = zr[c] + zr[P + c] + zr[2 * P + c] + zr[3 * P + c] + bb[cc];
    }
  }
}

extern "C" void kernel_launch(void* const* d_in, const int* in_sizes, int n_in,
                              void* d_out, int out_size, void* d_ws, size_t ws_size,
                              hipStream_t stream) {
  char* ws = (char*)d_ws;
  // phase-1 (staging)
  H16* fT2    = (H16*)(ws);                    // 67108864
  H16* fT3    = (H16*)(ws + 67108864);         // 16777216
  H16* fT4    = (H16*)(ws + 83886080);         //  4194304
  H16* fT5    = (H16*)(ws + 88080384);         //  1048576
  H16* w1t    = (H16*)(ws + 89128960);         // 25690112
  H16* pooled = (H16*)(ws + 114819072);        // 51380224  (end 166199296)
  // phase-2 (fT* dead after roialign)
  float* part1 = (float*)(ws);                 // 67108864 = 8 x 2048x1024 f32
  float* x1    = (float*)(ws + 67108864);      //  8388608
  H16*   y1    = (H16*)(ws + 75497472);        //  4194304
  H16*   w2b   = (H16*)(ws + 83886080);        //  2097152
  H16*   w3b   = (H16*)(ws + 85983232);        //  1048576
  float* psum  = (float*)(ws + 87031808);      //  1024000 (250x1024)
  float* psq   = (float*)(ws + 88055808);      //  1024000 (end 89079808)
  float* coef1 = (float*)(ws + 89079808);      //    16384
  float* coef2 = (float*)(ws + 89096192);      //    16384 (< 89128960 OK)
  // phase-3 (pooled + w1t dead after conv1 gemm)
  float* x2    = (float*)(ws + 89128960);      //  8388608
  H16*   y2    = (H16*)(ws + 97517568);        //  4194304 (end 101711872)
  float* part2 = (float*)(ws + 114819072);     // 33554432 = 4 x 2048x1024 f32
  // phase-4 (part1 region dead after conv2 reduce)
  float* zhead = (float*)(ws);                 // 16777216 = 4 x 2048x512 f32

  const float* rois = (const float*)d_in[0];

  k_transpose_all<<<5440, 256, 0, stream>>>(
      (const float*)d_in[1], (const float*)d_in[2],
      (const float*)d_in[3], (const float*)d_in[4], fT2, fT3, fT4, fT5);
  k_prep_w1<<<1024, 256, 0, stream>>>((const float*)d_in[5], w1t);
  k_roialign<<<2048, 256, 0, stream>>>(rois, fT2, fT3, fT4, fT5, pooled);
  k_prep_small<<<1536, 256, 0, stream>>>((const float4*)d_in[9],
      (const float4*)d_in[13], (const float4*)d_in[15], (uint2*)w2b, (uint2*)w3b);

  // conv1: 2048 x 1024 x 12544, split-K=8 -> 1024 blocks (4/CU)
  k_gemm<<<dim3(16, 8, 8), 256, 0, stream>>>(pooled, w1t, part1, 1024, 12544, 1568);
  k_red_stats<<<250, 256, 0, stream>>>(part1, x1, psum, psq, 8);
  k_bn_fin<<<8, 256, 0, stream>>>(psum, psq, (const float*)d_in[7], (const float*)d_in[8], coef1);
  k_bn_apply<<<2048, 256, 0, stream>>>(x1, coef1, y1);

  // conv2: 2048 x 1024 x 1024, split-K=4 -> 512 blocks
  k_gemm<<<dim3(16, 8, 4), 256, 0, stream>>>(y1, w2b, part2, 1024, 1024, 256);
  k_red_stats<<<250, 256, 0, stream>>>(part2, x2, psum, psq, 4);
  k_bn_fin<<<8, 256, 0, stream>>>(psum, psq, (const float*)d_in[11], (const float*)d_in[12], coef2);
  k_bn_apply<<<2048, 256, 0, stream>>>(x2, coef2, y2);

  // heads: 2048 x 512 x 1024, split-K=4 -> 256 blocks; reduce fused into k_head
  k_gemm<<<dim3(16, 4, 4), 256, 0, stream>>>(y2, w3b, zhead, 512, 1024, 256);
  k_head<<<2000, 64, 0, stream>>>(zhead, (const float*)d_in[14], (const float*)d_in[16], (float*)d_out);
}